// Round 6
// baseline (6733.498 us; speedup 1.0000x reference)
//
#include <hip/hip_runtime.h>
#include <hip/hip_bf16.h>
#include <stdint.h>

using bf16 = __hip_bfloat16;
typedef __attribute__((ext_vector_type(8))) short short8;
typedef __attribute__((ext_vector_type(4))) float floatx4;

constexpr int BATCH = 2;
constexpr int SEQ   = 2048;
constexpr int NH    = 16;
constexpr int DH    = 64;
constexpr int DM    = 1024;
constexpr int MROWS = BATCH * SEQ;   // 4096
constexpr int OUTN  = MROWS * DM;    // 4194304

__device__ inline short bfbits(float x) {
    bf16 h = __float2bfloat16(x);
    return __builtin_bit_cast(short, h);
}
__device__ inline short8 frag8f(const float* p) {
    short8 r;
    #pragma unroll
    for (int i = 0; i < 8; i++) r[i] = bfbits(p[i]);
    return r;
}

// ============ MFMA GEMM 1: QKV projection ============
// C[M,N] = x[M,K] * W[N,K]^T  (reference orientation, dict weight order)
// outputs head-scattered bf16 [B,H,S,DH]; z = blockIdx.z selects (wq,q)(wk,k)(wv,v)
__global__ __launch_bounds__(256)
void gemm_qkv(const float* __restrict__ A,
              const float* __restrict__ W0, const float* __restrict__ W1,
              const float* __restrict__ W2,
              bf16* __restrict__ C0, bf16* __restrict__ C1, bf16* __restrict__ C2)
{
    constexpr int LDA = 40;
    __shared__ __align__(16) bf16 As[128 * LDA];
    __shared__ __align__(16) bf16 Ws[128 * LDA];

    const int t    = threadIdx.x;
    const int wave = t >> 6;
    const int lane = t & 63;
    const int quad = lane >> 4;
    const int l16  = lane & 15;
    const int m0 = blockIdx.y * 128;
    const int n0 = blockIdx.x * 128;
    const int wr = (wave >> 1) * 64;
    const int wc = (wave & 1) * 64;

    const int z = blockIdx.z;
    const float* W = (z == 0) ? W0 : ((z == 1) ? W1 : W2);
    bf16*        C = (z == 0) ? C0 : ((z == 1) ? C1 : C2);

    const int srow = t >> 2;          // 0..63
    const int scol = (t & 3) * 8;     // 0,8,16,24

    floatx4 acc[4][4] = {};

    for (int k0 = 0; k0 < DM; k0 += 32) {
        short8 a0 = frag8f(A + (size_t)(m0 + srow) * DM + k0 + scol);
        short8 a1 = frag8f(A + (size_t)(m0 + 64 + srow) * DM + k0 + scol);
        short8 w0 = frag8f(W + (size_t)(n0 + srow) * DM + k0 + scol);
        short8 w1 = frag8f(W + (size_t)(n0 + 64 + srow) * DM + k0 + scol);
        __syncthreads();
        *(short8*)(As + srow * LDA + scol)        = a0;
        *(short8*)(As + (64 + srow) * LDA + scol) = a1;
        *(short8*)(Ws + srow * LDA + scol)        = w0;
        *(short8*)(Ws + (64 + srow) * LDA + scol) = w1;
        __syncthreads();

        short8 af[4], wf[4];
        #pragma unroll
        for (int i = 0; i < 4; i++)
            af[i] = *(const short8*)(As + (wr + i * 16 + l16) * LDA + quad * 8);
        #pragma unroll
        for (int j = 0; j < 4; j++)
            wf[j] = *(const short8*)(Ws + (wc + j * 16 + l16) * LDA + quad * 8);
        #pragma unroll
        for (int i = 0; i < 4; i++)
            #pragma unroll
            for (int j = 0; j < 4; j++)
                acc[i][j] = __builtin_amdgcn_mfma_f32_16x16x32_bf16(af[i], wf[j], acc[i][j], 0, 0, 0);
    }

    // C/D layout: col = lane&15, row = quad*4 + reg  [m89/m91]
    #pragma unroll
    for (int i = 0; i < 4; i++) {
        #pragma unroll
        for (int j = 0; j < 4; j++) {
            #pragma unroll
            for (int r = 0; r < 4; r++) {
                const int gm = m0 + wr + i * 16 + quad * 4 + r;
                const int gn = n0 + wc + j * 16 + l16;
                const int b = gm >> 11, s = gm & (SEQ - 1);
                const int h = gn >> 6,  d = gn & (DH - 1);
                C[(((size_t)(b * NH + h)) * SEQ + s) * DH + d] = __float2bfloat16(acc[i][j][r]);
            }
        }
    }
}

// ============ MFMA GEMM 2: out-projection ============
// out[M,N] = attn[M,K] * wo[N,K]^T ; attn stored [B,H,S,DH] bf16 (k = h*64+d);
// output FLOAT32 row-major [B,S,DM].
__global__ __launch_bounds__(256)
void gemm_out(const bf16* __restrict__ A, const float* __restrict__ W,
              float* __restrict__ C)
{
    constexpr int LDA = 40;
    __shared__ __align__(16) bf16 As[128 * LDA];
    __shared__ __align__(16) bf16 Ws[128 * LDA];

    const int t    = threadIdx.x;
    const int wave = t >> 6;
    const int lane = t & 63;
    const int quad = lane >> 4;
    const int l16  = lane & 15;
    const int m0 = blockIdx.y * 128;
    const int n0 = blockIdx.x * 128;
    const int wr = (wave >> 1) * 64;
    const int wc = (wave & 1) * 64;

    const int srow = t >> 2;
    const int scol = (t & 3) * 8;

    floatx4 acc[4][4] = {};

    for (int k0 = 0; k0 < DM; k0 += 32) {
        // A rows live in [B,H,S,DH]: k = h*64+d, 8 contiguous within a head
        const int k  = k0 + scol;
        const int h  = k >> 6, d = k & (DH - 1);
        const int m1 = m0 + srow, m2 = m0 + 64 + srow;
        const int b1 = m1 >> 11, s1 = m1 & (SEQ - 1);
        const int b2 = m2 >> 11, s2 = m2 & (SEQ - 1);
        short8 a0 = *(const short8*)(A + (((size_t)(b1 * NH + h)) * SEQ + s1) * DH + d);
        short8 a1 = *(const short8*)(A + (((size_t)(b2 * NH + h)) * SEQ + s2) * DH + d);
        short8 w0 = frag8f(W + (size_t)(n0 + srow) * DM + k0 + scol);
        short8 w1 = frag8f(W + (size_t)(n0 + 64 + srow) * DM + k0 + scol);
        __syncthreads();
        *(short8*)(As + srow * LDA + scol)        = a0;
        *(short8*)(As + (64 + srow) * LDA + scol) = a1;
        *(short8*)(Ws + srow * LDA + scol)        = w0;
        *(short8*)(Ws + (64 + srow) * LDA + scol) = w1;
        __syncthreads();

        short8 af[4], wf[4];
        #pragma unroll
        for (int i = 0; i < 4; i++)
            af[i] = *(const short8*)(As + (wr + i * 16 + l16) * LDA + quad * 8);
        #pragma unroll
        for (int j = 0; j < 4; j++)
            wf[j] = *(const short8*)(Ws + (wc + j * 16 + l16) * LDA + quad * 8);
        #pragma unroll
        for (int i = 0; i < 4; i++)
            #pragma unroll
            for (int j = 0; j < 4; j++)
                acc[i][j] = __builtin_amdgcn_mfma_f32_16x16x32_bf16(af[i], wf[j], acc[i][j], 0, 0, 0);
    }

    #pragma unroll
    for (int i = 0; i < 4; i++)
        #pragma unroll
        for (int j = 0; j < 4; j++)
            #pragma unroll
            for (int r = 0; r < 4; r++) {
                const int gm = m0 + wr + i * 16 + quad * 4 + r;
                const int gn = n0 + wc + j * 16 + l16;
                C[(size_t)gm * DM + gn] = acc[i][j][r];   // fp32 store
            }
}

// ============ naive causal attention, in-place on Q [B,H,S,DH] ============
// one wave per (qrow, h, b); lane = dim. Each block reads/writes ONLY its own Q row.
__global__ __launch_bounds__(64)
void attn_naive(bf16* __restrict__ Q, const bf16* __restrict__ K,
                const bf16* __restrict__ V)
{
    __shared__ float sc[SEQ];

    const int lane = threadIdx.x;
    const int qrow = blockIdx.x;
    const int h    = blockIdx.y;
    const int b    = blockIdx.z;
    const size_t bh = ((size_t)(b * NH + h)) * SEQ * DH;

    const float qd = __bfloat162float(Q[bh + (size_t)qrow * DH + lane]);

    float m = -1e30f;
    for (int key = 0; key <= qrow; ++key) {
        float s = qd * __bfloat162float(K[bh + (size_t)key * DH + lane]);
        #pragma unroll
        for (int d = 1; d < 64; d <<= 1) s += __shfl_xor(s, d, 64);
        s *= 0.125f;                     // 1/sqrt(64)
        if (lane == 0) sc[key] = s;
        m = fmaxf(m, s);
    }
    __syncthreads();

    float lsum = 0.f;
    for (int key = lane; key <= qrow; key += 64) {
        const float p = __expf(sc[key] - m);
        sc[key] = p;
        lsum += p;
    }
    #pragma unroll
    for (int d = 1; d < 64; d <<= 1) lsum += __shfl_xor(lsum, d, 64);
    __syncthreads();

    float o = 0.f;
    for (int key = 0; key <= qrow; ++key)
        o += sc[key] * __bfloat162float(V[bh + (size_t)key * DH + lane]);

    Q[bh + (size_t)qrow * DH + lane] = __float2bfloat16(o / lsum);  // in place
}

extern "C" void kernel_launch(void* const* d_in, const int* in_sizes, int n_in,
                              void* d_out, int out_size, void* d_ws, size_t ws_size,
                              hipStream_t stream)
{
    const float* x  = (const float*)d_in[0];
    const float* wq = (const float*)d_in[1];
    const float* wk = (const float*)d_in[2];
    const float* wv = (const float*)d_in[3];
    const float* wo = (const float*)d_in[4];
    float* out = (float*)d_out;            // reference output dtype = float32

    // ws: q | k | v  bf16 [B,H,S,DH], 8 MB each (ws >= 24 MB verified in R5)
    bf16* qb = (bf16*)d_ws;
    bf16* kb = qb + (size_t)OUTN;
    bf16* vb = kb + (size_t)OUTN;

    gemm_qkv<<<dim3(DM / 128, MROWS / 128, 3), dim3(256), 0, stream>>>(
        x, wq, wk, wv, qb, kb, vb);
    attn_naive<<<dim3(SEQ, NH, BATCH), dim3(64), 0, stream>>>(qb, kb, vb);
    gemm_out<<<dim3(DM / 128, MROWS / 128, 1), dim3(256), 0, stream>>>(
        qb, wo, out);
}

// Round 7
// 279.962 us; speedup vs baseline: 24.0515x; 24.0515x over previous
//
#include <hip/hip_runtime.h>
#include <hip/hip_bf16.h>
#include <stdint.h>

using bf16 = __hip_bfloat16;
typedef __attribute__((ext_vector_type(8))) short short8;
typedef __attribute__((ext_vector_type(4))) float floatx4;
typedef __attribute__((ext_vector_type(4))) unsigned int uintx4;

constexpr int BATCH = 2;
constexpr int SEQ   = 2048;
constexpr int NH    = 16;
constexpr int DH    = 64;
constexpr int DM    = 1024;
constexpr int MROWS = BATCH * SEQ;   // 4096
constexpr int OUTN  = MROWS * DM;    // 4194304

__device__ inline short bfbits(float x) {
    bf16 h = __float2bfloat16(x);
    return __builtin_bit_cast(short, h);
}
__device__ inline short8 frag8f(const float* p) {
    short8 r;
    #pragma unroll
    for (int i = 0; i < 8; i++) r[i] = bfbits(p[i]);
    return r;
}

// ============ MFMA GEMM 1: QKV projection ============
// C[M,N] = x[M,K] * W[N,K]^T;  z selects (wq,q)(wk,k)(wv,vT)
// q,k head-scattered [B,H,S,DH]; v TRANSPOSED [B,H,DH,S] for flash PV frags
__global__ __launch_bounds__(256)
void gemm_qkv(const float* __restrict__ A,
              const float* __restrict__ W0, const float* __restrict__ W1,
              const float* __restrict__ W2,
              bf16* __restrict__ C0, bf16* __restrict__ C1, bf16* __restrict__ C2)
{
    constexpr int LDA = 40;
    __shared__ __align__(16) bf16 As[128 * LDA];
    __shared__ __align__(16) bf16 Ws[128 * LDA];

    const int t    = threadIdx.x;
    const int wave = t >> 6;
    const int lane = t & 63;
    const int quad = lane >> 4;
    const int l16  = lane & 15;
    const int m0 = blockIdx.y * 128;
    const int n0 = blockIdx.x * 128;
    const int wr = (wave >> 1) * 64;
    const int wc = (wave & 1) * 64;

    const int z = blockIdx.z;
    const float* W = (z == 0) ? W0 : ((z == 1) ? W1 : W2);

    const int srow = t >> 2;          // 0..63
    const int scol = (t & 3) * 8;     // 0,8,16,24

    floatx4 acc[4][4] = {};

    for (int k0 = 0; k0 < DM; k0 += 32) {
        short8 a0 = frag8f(A + (size_t)(m0 + srow) * DM + k0 + scol);
        short8 a1 = frag8f(A + (size_t)(m0 + 64 + srow) * DM + k0 + scol);
        short8 w0 = frag8f(W + (size_t)(n0 + srow) * DM + k0 + scol);
        short8 w1 = frag8f(W + (size_t)(n0 + 64 + srow) * DM + k0 + scol);
        __syncthreads();
        *(short8*)(As + srow * LDA + scol)        = a0;
        *(short8*)(As + (64 + srow) * LDA + scol) = a1;
        *(short8*)(Ws + srow * LDA + scol)        = w0;
        *(short8*)(Ws + (64 + srow) * LDA + scol) = w1;
        __syncthreads();

        short8 af[4], wf[4];
        #pragma unroll
        for (int i = 0; i < 4; i++)
            af[i] = *(const short8*)(As + (wr + i * 16 + l16) * LDA + quad * 8);
        #pragma unroll
        for (int j = 0; j < 4; j++)
            wf[j] = *(const short8*)(Ws + (wc + j * 16 + l16) * LDA + quad * 8);
        #pragma unroll
        for (int i = 0; i < 4; i++)
            #pragma unroll
            for (int j = 0; j < 4; j++)
                acc[i][j] = __builtin_amdgcn_mfma_f32_16x16x32_bf16(af[i], wf[j], acc[i][j], 0, 0, 0);
    }

    // C/D layout: col = lane&15, row = quad*4 + reg  [m89/m91]
    #pragma unroll
    for (int i = 0; i < 4; i++) {
        #pragma unroll
        for (int j = 0; j < 4; j++) {
            #pragma unroll
            for (int r = 0; r < 4; r++) {
                const int gm = m0 + wr + i * 16 + quad * 4 + r;
                const int gn = n0 + wc + j * 16 + l16;
                const int b = gm >> 11, s = gm & (SEQ - 1);
                const int h = gn >> 6,  d = gn & (DH - 1);
                const bf16 val = __float2bfloat16(acc[i][j][r]);
                if (z == 2)
                    C2[(((size_t)(b * NH + h)) * DH + d) * SEQ + s] = val;  // V^T
                else if (z == 0)
                    C0[(((size_t)(b * NH + h)) * SEQ + s) * DH + d] = val;
                else
                    C1[(((size_t)(b * NH + h)) * SEQ + s) * DH + d] = val;
            }
        }
    }
}

// ============ MFMA GEMM 2: out-projection (verified R6) ============
// out[M,N] = attn[M,K] * wo[N,K]^T ; attn [B,H,S,DH] bf16; out fp32 [B,S,DM]
__global__ __launch_bounds__(256)
void gemm_out(const bf16* __restrict__ A, const float* __restrict__ W,
              float* __restrict__ C)
{
    constexpr int LDA = 40;
    __shared__ __align__(16) bf16 As[128 * LDA];
    __shared__ __align__(16) bf16 Ws[128 * LDA];

    const int t    = threadIdx.x;
    const int wave = t >> 6;
    const int lane = t & 63;
    const int quad = lane >> 4;
    const int l16  = lane & 15;
    const int m0 = blockIdx.y * 128;
    const int n0 = blockIdx.x * 128;
    const int wr = (wave >> 1) * 64;
    const int wc = (wave & 1) * 64;

    const int srow = t >> 2;
    const int scol = (t & 3) * 8;

    floatx4 acc[4][4] = {};

    for (int k0 = 0; k0 < DM; k0 += 32) {
        const int k  = k0 + scol;
        const int h  = k >> 6, d = k & (DH - 1);
        const int m1 = m0 + srow, m2 = m0 + 64 + srow;
        const int b1 = m1 >> 11, s1 = m1 & (SEQ - 1);
        const int b2 = m2 >> 11, s2 = m2 & (SEQ - 1);
        short8 a0 = *(const short8*)(A + (((size_t)(b1 * NH + h)) * SEQ + s1) * DH + d);
        short8 a1 = *(const short8*)(A + (((size_t)(b2 * NH + h)) * SEQ + s2) * DH + d);
        short8 w0 = frag8f(W + (size_t)(n0 + srow) * DM + k0 + scol);
        short8 w1 = frag8f(W + (size_t)(n0 + 64 + srow) * DM + k0 + scol);
        __syncthreads();
        *(short8*)(As + srow * LDA + scol)        = a0;
        *(short8*)(As + (64 + srow) * LDA + scol) = a1;
        *(short8*)(Ws + srow * LDA + scol)        = w0;
        *(short8*)(Ws + (64 + srow) * LDA + scol) = w1;
        __syncthreads();

        short8 af[4], wf[4];
        #pragma unroll
        for (int i = 0; i < 4; i++)
            af[i] = *(const short8*)(As + (wr + i * 16 + l16) * LDA + quad * 8);
        #pragma unroll
        for (int j = 0; j < 4; j++)
            wf[j] = *(const short8*)(Ws + (wc + j * 16 + l16) * LDA + quad * 8);
        #pragma unroll
        for (int i = 0; i < 4; i++)
            #pragma unroll
            for (int j = 0; j < 4; j++)
                acc[i][j] = __builtin_amdgcn_mfma_f32_16x16x32_bf16(af[i], wf[j], acc[i][j], 0, 0, 0);
    }

    #pragma unroll
    for (int i = 0; i < 4; i++)
        #pragma unroll
        for (int j = 0; j < 4; j++)
            #pragma unroll
            for (int r = 0; r < 4; r++) {
                const int gm = m0 + wr + i * 16 + quad * 4 + r;
                const int gn = n0 + wc + j * 16 + l16;
                C[(size_t)gm * DM + gn] = acc[i][j][r];
            }
}

// ============ MFMA causal flash attention, in-place on Q [B,H,S,DH] ============
// grid (S/64, H, B), 4 waves; wave w owns q rows [q0+16w, q0+16w+16)
__global__ __launch_bounds__(256)
void attn_flash(bf16* __restrict__ Q, const bf16* __restrict__ K,
                const bf16* __restrict__ Vt)
{
    constexpr int LK = 72;   // 64 + 8 pad
    __shared__ __align__(16) bf16 Ks[64 * LK];      // [key][dim]
    __shared__ __align__(16) bf16 Vs[64 * LK];      // [dim][key]
    __shared__ __align__(16) bf16 Ps[4][16 * LK];   // per-wave P round-trip

    const int t    = threadIdx.x;
    const int wave = t >> 6;
    const int lane = t & 63;
    const int quad = lane >> 4;
    const int l16  = lane & 15;

    const int q0 = blockIdx.x * 64;
    const int h  = blockIdx.y;
    const int b  = blockIdx.z;
    const size_t bh = ((size_t)(b * NH + h)) * SEQ * DH;

    const int qrow = q0 + wave * 16;

    // A-frags of Q held in registers; loaded before any write to Q
    short8 qf0 = *(const short8*)(Q + bh + (size_t)(qrow + l16) * DH + quad * 8);
    short8 qf1 = *(const short8*)(Q + bh + (size_t)(qrow + l16) * DH + quad * 8 + 32);

    floatx4 oacc[4] = {};
    float mrow[4], lrow[4];
    #pragma unroll
    for (int r = 0; r < 4; r++) { mrow[r] = -1e30f; lrow[r] = 0.f; }

    const int stage_r = t >> 3;        // 0..31
    const int stage_c = (t & 7) * 8;   // 0..56

    for (int k0 = 0; k0 < q0 + 64; k0 += 64) {
        uintx4 kv0 = *(const uintx4*)(K  + bh + (size_t)(k0 + stage_r) * DH + stage_c);
        uintx4 kv1 = *(const uintx4*)(K  + bh + (size_t)(k0 + 32 + stage_r) * DH + stage_c);
        uintx4 vv0 = *(const uintx4*)(Vt + bh + (size_t)stage_r * SEQ + k0 + stage_c);
        uintx4 vv1 = *(const uintx4*)(Vt + bh + (size_t)(stage_r + 32) * SEQ + k0 + stage_c);
        __syncthreads();
        *(uintx4*)(Ks + stage_r * LK + stage_c)        = kv0;
        *(uintx4*)(Ks + (32 + stage_r) * LK + stage_c) = kv1;
        *(uintx4*)(Vs + stage_r * LK + stage_c)        = vv0;
        *(uintx4*)(Vs + (32 + stage_r) * LK + stage_c) = vv1;
        __syncthreads();

        if (k0 <= qrow + 15) {
            // ---- scores S[16 x 64] = Q K^T ----
            floatx4 sc[4];
            #pragma unroll
            for (int j = 0; j < 4; j++) {
                short8 kf0 = *(const short8*)(Ks + (j * 16 + l16) * LK + quad * 8);
                short8 kf1 = *(const short8*)(Ks + (j * 16 + l16) * LK + quad * 8 + 32);
                floatx4 c = {};
                c = __builtin_amdgcn_mfma_f32_16x16x32_bf16(qf0, kf0, c, 0, 0, 0);
                c = __builtin_amdgcn_mfma_f32_16x16x32_bf16(qf1, kf1, c, 0, 0, 0);
                sc[j] = c;
            }
            // ---- scale + causal mask ----
            #pragma unroll
            for (int j = 0; j < 4; j++) {
                const int kg = k0 + j * 16 + l16;
                #pragma unroll
                for (int r = 0; r < 4; r++) {
                    const int qg = qrow + quad * 4 + r;
                    const float sv = sc[j][r] * 0.125f;   // 1/sqrt(64)
                    sc[j][r] = (kg <= qg) ? sv : -1e30f;
                }
            }
            // ---- online softmax (16-lane butterfly within quad) ----
            #pragma unroll
            for (int r = 0; r < 4; r++) {
                float mx = fmaxf(fmaxf(sc[0][r], sc[1][r]), fmaxf(sc[2][r], sc[3][r]));
                #pragma unroll
                for (int d = 1; d < 16; d <<= 1) mx = fmaxf(mx, __shfl_xor(mx, d, 64));
                const float mnew  = fmaxf(mrow[r], mx);
                const float alpha = __expf(mrow[r] - mnew);
                float rs = 0.f;
                #pragma unroll
                for (int j = 0; j < 4; j++) {
                    const float p = __expf(sc[j][r] - mnew);
                    sc[j][r] = p;
                    rs += p;
                }
                #pragma unroll
                for (int d = 1; d < 16; d <<= 1) rs += __shfl_xor(rs, d, 64);
                lrow[r] = lrow[r] * alpha + rs;
                mrow[r] = mnew;
                #pragma unroll
                for (int td = 0; td < 4; td++) oacc[td][r] *= alpha;
            }
            // ---- P: C-layout -> A-layout via per-wave LDS (m120 pattern) ----
            bf16* P = &Ps[wave][0];
            #pragma unroll
            for (int j = 0; j < 4; j++)
                #pragma unroll
                for (int r = 0; r < 4; r++)
                    P[(quad * 4 + r) * LK + j * 16 + l16] = __float2bfloat16(sc[j][r]);
            // ---- PV: O += P[16x64] * V[64x64] ----
            #pragma unroll
            for (int ks = 0; ks < 2; ks++) {
                short8 pa = *(const short8*)(P + l16 * LK + ks * 32 + quad * 8);
                #pragma unroll
                for (int td = 0; td < 4; td++) {
                    short8 vf = *(const short8*)(Vs + (td * 16 + l16) * LK + ks * 32 + quad * 8);
                    oacc[td] = __builtin_amdgcn_mfma_f32_16x16x32_bf16(pa, vf, oacc[td], 0, 0, 0);
                }
            }
        }
    }

    // epilogue: O /= l, in-place into Q's [B,H,S,DH] slots (own rows only)
    #pragma unroll
    for (int td = 0; td < 4; td++) {
        #pragma unroll
        for (int r = 0; r < 4; r++) {
            const int qg = qrow + quad * 4 + r;
            Q[bh + (size_t)qg * DH + td * 16 + l16] =
                __float2bfloat16(oacc[td][r] / lrow[r]);
        }
    }
}

extern "C" void kernel_launch(void* const* d_in, const int* in_sizes, int n_in,
                              void* d_out, int out_size, void* d_ws, size_t ws_size,
                              hipStream_t stream)
{
    const float* x  = (const float*)d_in[0];
    const float* wq = (const float*)d_in[1];
    const float* wk = (const float*)d_in[2];
    const float* wv = (const float*)d_in[3];
    const float* wo = (const float*)d_in[4];
    float* out = (float*)d_out;            // fp32 output (verified R6)

    // ws: q | k | vT  bf16, 8 MB each
    bf16* qb = (bf16*)d_ws;
    bf16* kb = qb + (size_t)OUTN;
    bf16* vb = kb + (size_t)OUTN;

    gemm_qkv<<<dim3(DM / 128, MROWS / 128, 3), dim3(256), 0, stream>>>(
        x, wq, wk, wv, qb, kb, vb);
    attn_flash<<<dim3(SEQ / 64, NH, BATCH), dim3(256), 0, stream>>>(qb, kb, vb);
    gemm_out<<<dim3(DM / 128, MROWS / 128, 1), dim3(256), 0, stream>>>(
        qb, wo, out);
}

// Round 8
// 234.260 us; speedup vs baseline: 28.7437x; 1.1951x over previous
//
#include <hip/hip_runtime.h>
#include <hip/hip_bf16.h>
#include <stdint.h>

using bf16 = __hip_bfloat16;
typedef __attribute__((ext_vector_type(8))) short short8;
typedef __attribute__((ext_vector_type(4))) float floatx4;
typedef __attribute__((ext_vector_type(4))) unsigned int uintx4;

constexpr int BATCH = 2;
constexpr int SEQ   = 2048;
constexpr int NH    = 16;
constexpr int DH    = 64;
constexpr int DM    = 1024;
constexpr int MROWS = BATCH * SEQ;        // 4096
constexpr int OUTN  = MROWS * DM;         // 4194304
constexpr int WN    = DM * DM;            // 1048576

__device__ inline short bfbits(float x) {
    bf16 h = __float2bfloat16(x);
    return __builtin_bit_cast(short, h);
}

// async global->LDS, 16B per lane (m97 pattern; LDS dest = wave base + lane*16)
__device__ inline void async16(bf16* lds, const bf16* g) {
    __builtin_amdgcn_global_load_lds(
        (const __attribute__((address_space(1))) unsigned int*)g,
        (__attribute__((address_space(3))) unsigned int*)lds, 16, 0, 0);
}

// ============ fp32 -> bf16 pre-convert: x|wq|wk|wv into d_out scratch ============
__global__ __launch_bounds__(256)
void cvt_inputs(const float* __restrict__ x,  const float* __restrict__ wq,
                const float* __restrict__ wk, const float* __restrict__ wv,
                bf16* __restrict__ dst)
{
    const size_t i = ((size_t)blockIdx.x * 256 + threadIdx.x) * 8;  // grid sized exactly
    const float* src; size_t off;
    if (i < (size_t)OUTN)               { src = x;  off = i; }
    else if (i < (size_t)OUTN + WN)     { src = wq; off = i - OUTN; }
    else if (i < (size_t)OUTN + 2 * WN) { src = wk; off = i - OUTN - WN; }
    else                                { src = wv; off = i - OUTN - 2 * (size_t)WN; }
    float4 f0 = *(const float4*)(src + off);
    float4 f1 = *(const float4*)(src + off + 4);
    short8 o;
    o[0] = bfbits(f0.x); o[1] = bfbits(f0.y); o[2] = bfbits(f0.z); o[3] = bfbits(f0.w);
    o[4] = bfbits(f1.x); o[5] = bfbits(f1.y); o[6] = bfbits(f1.z); o[7] = bfbits(f1.w);
    *(short8*)(dst + i) = o;
}

__global__ __launch_bounds__(256)
void cvt_wo(const float* __restrict__ wo, bf16* __restrict__ dst)
{
    const size_t i = ((size_t)blockIdx.x * 256 + threadIdx.x) * 8;
    float4 f0 = *(const float4*)(wo + i);
    float4 f1 = *(const float4*)(wo + i + 4);
    short8 o;
    o[0] = bfbits(f0.x); o[1] = bfbits(f0.y); o[2] = bfbits(f0.z); o[3] = bfbits(f0.w);
    o[4] = bfbits(f1.x); o[5] = bfbits(f1.y); o[6] = bfbits(f1.z); o[7] = bfbits(f1.w);
    *(short8*)(dst + i) = o;
}

// ============ bf16 MFMA GEMM with global_load_lds staging (m97 structure) ============
// C[M,N] = A[M,K=1024] * W[N,K=1024]^T, 128x128 tile, BK=32.
// MODE 0: A = xb row-major; z selects (wq->q)(wk->k)(wv->vT); q,k [B,H,S,DH], vT [B,H,DH,S]
// MODE 1: A = attn-out gathered from [B,H,S,DH]; output fp32 row-major [B,S,DM]
template<int MODE>
__global__ __launch_bounds__(256)
void gemm_mfma(const bf16* __restrict__ A,
               const bf16* __restrict__ W0, const bf16* __restrict__ W1,
               const bf16* __restrict__ W2,
               bf16* __restrict__ C0, bf16* __restrict__ C1, bf16* __restrict__ C2,
               float* __restrict__ F)
{
    __shared__ __align__(16) bf16 As[128 * 32];   // unpadded: required by global_load_lds
    __shared__ __align__(16) bf16 Ws[128 * 32];   // (frag reads are conflict-minimal, see R8 notes)

    const int t    = threadIdx.x;
    const int wave = t >> 6;
    const int lane = t & 63;
    const int quad = lane >> 4;
    const int l16  = lane & 15;
    const int m0 = blockIdx.y * 128;
    const int n0 = blockIdx.x * 128;
    const int wr = (wave >> 1) * 64;
    const int wc = (wave & 1) * 64;

    const int z = (MODE == 0) ? blockIdx.z : 0;
    const bf16* W = (z == 0) ? W0 : ((z == 1) ? W1 : W2);

    // staging: chunk c = t and c+256; LDS offset = chunk*16B; row=chunk/4, col=(chunk%4)*8
    const int c    = t;
    bf16* lA0 = As + c * 8;          bf16* lA1 = As + c * 8 + 2048;
    bf16* lW0 = Ws + c * 8;          bf16* lW1 = Ws + c * 8 + 2048;
    const int ar0 = m0 + (c >> 2),  ar1 = m0 + 64 + (c >> 2);
    const int nr0 = n0 + (c >> 2),  nr1 = n0 + 64 + (c >> 2);
    const int kc  = (c & 3) * 8;

    floatx4 acc[4][4] = {};

    for (int k0 = 0; k0 < DM; k0 += 32) {
        const bf16 *gA0, *gA1;
        if (MODE == 0) {
            gA0 = A + (size_t)ar0 * DM + k0 + kc;
            gA1 = A + (size_t)ar1 * DM + k0 + kc;
        } else {
            const int k = k0 + kc, h = k >> 6, d = k & (DH - 1);
            gA0 = A + (((size_t)((ar0 >> 11) * NH + h)) * SEQ + (ar0 & (SEQ - 1))) * DH + d;
            gA1 = A + (((size_t)((ar1 >> 11) * NH + h)) * SEQ + (ar1 & (SEQ - 1))) * DH + d;
        }
        const bf16* gW0 = W + (size_t)nr0 * DM + k0 + kc;
        const bf16* gW1 = W + (size_t)nr1 * DM + k0 + kc;

        __syncthreads();                  // prior-iter frag reads done
        async16(lA0, gA0);
        async16(lA1, gA1);
        async16(lW0, gW0);
        async16(lW1, gW1);
        __syncthreads();                  // drains vmcnt -> LDS valid

        short8 af[4], wf[4];
        #pragma unroll
        for (int i = 0; i < 4; i++)
            af[i] = *(const short8*)(As + (wr + i * 16 + l16) * 32 + quad * 8);
        #pragma unroll
        for (int j = 0; j < 4; j++)
            wf[j] = *(const short8*)(Ws + (wc + j * 16 + l16) * 32 + quad * 8);
        #pragma unroll
        for (int i = 0; i < 4; i++)
            #pragma unroll
            for (int j = 0; j < 4; j++)
                acc[i][j] = __builtin_amdgcn_mfma_f32_16x16x32_bf16(af[i], wf[j], acc[i][j], 0, 0, 0);
    }

    // C/D layout: col = lane&15, row = quad*4 + reg  [m89/m91]
    #pragma unroll
    for (int i = 0; i < 4; i++) {
        #pragma unroll
        for (int j = 0; j < 4; j++) {
            #pragma unroll
            for (int r = 0; r < 4; r++) {
                const int gm = m0 + wr + i * 16 + quad * 4 + r;
                const int gn = n0 + wc + j * 16 + l16;
                if (MODE == 1) {
                    F[(size_t)gm * DM + gn] = acc[i][j][r];
                } else {
                    const int b = gm >> 11, s = gm & (SEQ - 1);
                    const int h = gn >> 6,  d = gn & (DH - 1);
                    const bf16 val = __float2bfloat16(acc[i][j][r]);
                    if (z == 2)
                        C2[(((size_t)(b * NH + h)) * DH + d) * SEQ + s] = val;   // V^T
                    else if (z == 0)
                        C0[(((size_t)(b * NH + h)) * SEQ + s) * DH + d] = val;
                    else
                        C1[(((size_t)(b * NH + h)) * SEQ + s) * DH + d] = val;
                }
            }
        }
    }
}

// ============ MFMA causal flash attention, in-place on Q [B,H,S,DH] ============
// grid (32, NH, BATCH); qt swizzled so each CU gets a balanced mix of diag depths
__global__ __launch_bounds__(256)
void attn_flash(bf16* __restrict__ Q, const bf16* __restrict__ K,
                const bf16* __restrict__ Vt)
{
    constexpr int LK = 72;   // 64 + 8 pad (16B-aligned rows)
    __shared__ __align__(16) bf16 Ks[64 * LK];      // [key][dim]
    __shared__ __align__(16) bf16 Vs[64 * LK];      // [dim][key]
    __shared__ __align__(16) bf16 Ps[4][16 * LK];   // per-wave P round-trip

    const int t    = threadIdx.x;
    const int wave = t >> 6;
    const int lane = t & 63;
    const int quad = lane >> 4;
    const int l16  = lane & 15;

    const int h  = blockIdx.y;
    const int b  = blockIdx.z;
    const int qt = (blockIdx.x + 5 * h + 16 * b) & 31;   // load-balance swizzle
    const int q0 = qt * 64;
    const size_t bh = ((size_t)(b * NH + h)) * SEQ * DH;

    const int qrow = q0 + wave * 16;

    short8 qf0 = *(const short8*)(Q + bh + (size_t)(qrow + l16) * DH + quad * 8);
    short8 qf1 = *(const short8*)(Q + bh + (size_t)(qrow + l16) * DH + quad * 8 + 32);

    floatx4 oacc[4] = {};
    float mrow[4], lrow[4];
    #pragma unroll
    for (int r = 0; r < 4; r++) { mrow[r] = -1e30f; lrow[r] = 0.f; }

    const int stage_r = t >> 3;        // 0..31
    const int stage_c = (t & 7) * 8;   // 0..56

    for (int k0 = 0; k0 < q0 + 64; k0 += 64) {
        uintx4 kv0 = *(const uintx4*)(K  + bh + (size_t)(k0 + stage_r) * DH + stage_c);
        uintx4 kv1 = *(const uintx4*)(K  + bh + (size_t)(k0 + 32 + stage_r) * DH + stage_c);
        uintx4 vv0 = *(const uintx4*)(Vt + bh + (size_t)stage_r * SEQ + k0 + stage_c);
        uintx4 vv1 = *(const uintx4*)(Vt + bh + (size_t)(stage_r + 32) * SEQ + k0 + stage_c);
        __syncthreads();
        *(uintx4*)(Ks + stage_r * LK + stage_c)        = kv0;
        *(uintx4*)(Ks + (32 + stage_r) * LK + stage_c) = kv1;
        *(uintx4*)(Vs + stage_r * LK + stage_c)        = vv0;
        *(uintx4*)(Vs + (32 + stage_r) * LK + stage_c) = vv1;
        __syncthreads();

        if (k0 <= qrow + 15) {
            floatx4 sc[4];
            #pragma unroll
            for (int j = 0; j < 4; j++) {
                short8 kf0 = *(const short8*)(Ks + (j * 16 + l16) * LK + quad * 8);
                short8 kf1 = *(const short8*)(Ks + (j * 16 + l16) * LK + quad * 8 + 32);
                floatx4 cc = {};
                cc = __builtin_amdgcn_mfma_f32_16x16x32_bf16(qf0, kf0, cc, 0, 0, 0);
                cc = __builtin_amdgcn_mfma_f32_16x16x32_bf16(qf1, kf1, cc, 0, 0, 0);
                sc[j] = cc;
            }
            #pragma unroll
            for (int j = 0; j < 4; j++) {
                const int kg = k0 + j * 16 + l16;
                #pragma unroll
                for (int r = 0; r < 4; r++) {
                    const int qg = qrow + quad * 4 + r;
                    const float sv = sc[j][r] * 0.125f;
                    sc[j][r] = (kg <= qg) ? sv : -1e30f;
                }
            }
            #pragma unroll
            for (int r = 0; r < 4; r++) {
                float mx = fmaxf(fmaxf(sc[0][r], sc[1][r]), fmaxf(sc[2][r], sc[3][r]));
                #pragma unroll
                for (int d = 1; d < 16; d <<= 1) mx = fmaxf(mx, __shfl_xor(mx, d, 64));
                const float mnew  = fmaxf(mrow[r], mx);
                const float alpha = __expf(mrow[r] - mnew);
                float rs = 0.f;
                #pragma unroll
                for (int j = 0; j < 4; j++) {
                    const float p = __expf(sc[j][r] - mnew);
                    sc[j][r] = p;
                    rs += p;
                }
                #pragma unroll
                for (int d = 1; d < 16; d <<= 1) rs += __shfl_xor(rs, d, 64);
                lrow[r] = lrow[r] * alpha + rs;
                mrow[r] = mnew;
                #pragma unroll
                for (int td = 0; td < 4; td++) oacc[td][r] *= alpha;
            }
            bf16* P = &Ps[wave][0];
            #pragma unroll
            for (int j = 0; j < 4; j++)
                #pragma unroll
                for (int r = 0; r < 4; r++)
                    P[(quad * 4 + r) * LK + j * 16 + l16] = __float2bfloat16(sc[j][r]);
            #pragma unroll
            for (int ks = 0; ks < 2; ks++) {
                short8 pa = *(const short8*)(P + l16 * LK + ks * 32 + quad * 8);
                #pragma unroll
                for (int td = 0; td < 4; td++) {
                    short8 vf = *(const short8*)(Vs + (td * 16 + l16) * LK + ks * 32 + quad * 8);
                    oacc[td] = __builtin_amdgcn_mfma_f32_16x16x32_bf16(pa, vf, oacc[td], 0, 0, 0);
                }
            }
        }
    }

    #pragma unroll
    for (int td = 0; td < 4; td++) {
        #pragma unroll
        for (int r = 0; r < 4; r++) {
            const int qg = qrow + quad * 4 + r;
            Q[bh + (size_t)qg * DH + td * 16 + l16] =
                __float2bfloat16(oacc[td][r] / lrow[r]);
        }
    }
}

extern "C" void kernel_launch(void* const* d_in, const int* in_sizes, int n_in,
                              void* d_out, int out_size, void* d_ws, size_t ws_size,
                              hipStream_t stream)
{
    const float* x  = (const float*)d_in[0];
    const float* wq = (const float*)d_in[1];
    const float* wk = (const float*)d_in[2];
    const float* wv = (const float*)d_in[3];
    const float* wo = (const float*)d_in[4];
    float* out = (float*)d_out;

    // ws (24 MB): q | k | vT  bf16
    bf16* qb = (bf16*)d_ws;
    bf16* kb = qb + (size_t)OUTN;
    bf16* vb = kb + (size_t)OUTN;

    // d_out (16 MB fp32) doubles as bf16 scratch for converted inputs until the
    // final GEMM overwrites it: xb(4M) | wqb(1M) | wkb(1M) | wvb(1M) bf16
    bf16* xb  = (bf16*)d_out;
    bf16* wqb = xb + (size_t)OUTN;
    bf16* wkb = wqb + WN;
    bf16* wvb = wkb + WN;

    cvt_inputs<<<(OUTN + 3 * WN) / (8 * 256), 256, 0, stream>>>(x, wq, wk, wv, xb);
    gemm_mfma<0><<<dim3(DM / 128, MROWS / 128, 3), dim3(256), 0, stream>>>(
        xb, wqb, wkb, wvb, qb, kb, vb, nullptr);
    attn_flash<<<dim3(SEQ / 64, NH, BATCH), dim3(256), 0, stream>>>(qb, kb, vb);
    // kb is dead after attention: reuse it for bf16 wo
    bf16* wob = kb;
    cvt_wo<<<WN / (8 * 256), 256, 0, stream>>>(wo, wob);
    gemm_mfma<1><<<dim3(DM / 128, MROWS / 128, 1), dim3(256), 0, stream>>>(
        qb, wob, nullptr, nullptr, nullptr, nullptr, nullptr, out);
}